// Round 2
// baseline (1665.842 us; speedup 1.0000x reference)
//
#include <hip/hip_runtime.h>
#include <stdint.h>

typedef __attribute__((ext_vector_type(8))) short bf16x8;  // 8 bf16 in 4 VGPRs
typedef __attribute__((ext_vector_type(4))) float f32x4;

// f32 -> bf16 round-to-nearest-even (values are normal; no NaN handling needed)
__device__ __forceinline__ ushort f2bf(float f) {
    uint32_t u = __float_as_uint(f);
    return (ushort)((u + 0x7FFFu + ((u >> 16) & 1u)) >> 16);
}

// ---------------- level metadata (from torch-ngp GridEncoder __init__) -------
__device__ const int d_level_off[16] = {
    0, 4920, 40864, 315496, 839784, 1364072, 1888360, 2412648,
    2936936, 3461224, 3985512, 4509800, 5034088, 5558376, 6082664, 6606952
};

// ---------------- grid encode + affordance embedding -> bf16 comb ------------
// one thread per (point, level); writes comb[n, l*8 .. l*8+7] as bf16.
// rows [npts, npts_pad) are zero-filled so the MFMA GEMM needs no row guards.
__global__ __launch_bounds__(256) void grid_encode_kernel(
    const float* __restrict__ x, const float* __restrict__ aff,
    const float* __restrict__ table, const float* __restrict__ Wa,
    const float* __restrict__ ba, ushort* __restrict__ comb,
    int npts, int npts_pad)
{
    int t = blockIdx.x * 256 + threadIdx.x;
    int n = t >> 4;
    if (n >= npts_pad) return;
    int l = t & 15;
    int fb = l * 8;
    uint32_t pk[4] = {0u, 0u, 0u, 0u};

    if (n < npts) {
        float scale = (float)((16 << l) - 1);
        float fr[3];
        uint32_t cc[3];
        #pragma unroll
        for (int d = 0; d < 3; ++d) {
            float b   = (x[n * 3 + d] + 10.0f) / 20.0f;   // [-10,10] -> [0,1]
            float x01 = (b + 1.0f) * 0.5f;                // -> [0.5,1]
            float pos = x01 * scale + 0.5f;
            float pg  = floorf(pos);
            fr[d] = pos - pg;
            cc[d] = (uint32_t)(int)pg;
        }

        const bool dense = (l < 3);
        const uint32_t s1 = (uint32_t)(16 << l) + 1u;
        const uint32_t s2 = s1 * s1;
        const int off = d_level_off[l];

        float fa[8] = {0.f, 0.f, 0.f, 0.f, 0.f, 0.f, 0.f, 0.f};
        #pragma unroll
        for (int c = 0; c < 8; ++c) {
            uint32_t cx = cc[0] + (uint32_t)(c & 1);
            uint32_t cy = cc[1] + (uint32_t)((c >> 1) & 1);
            uint32_t cz = cc[2] + (uint32_t)((c >> 2) & 1);
            float w = ((c & 1) ? fr[0] : 1.0f - fr[0])
                    * ((c & 2) ? fr[1] : 1.0f - fr[1])
                    * ((c & 4) ? fr[2] : 1.0f - fr[2]);
            uint32_t idx;
            if (dense) idx = cx + cy * s1 + cz * s2;
            else       idx = (cx ^ (cy * 2654435761u) ^ (cz * 805459861u)) & 0x7FFFFu;
            const float4* p = (const float4*)(table + (size_t)(idx + (uint32_t)off) * 8u);
            float4 t0 = p[0];
            float4 t1 = p[1];
            fa[0] = fmaf(w, t0.x, fa[0]);
            fa[1] = fmaf(w, t0.y, fa[1]);
            fa[2] = fmaf(w, t0.z, fa[2]);
            fa[3] = fmaf(w, t0.w, fa[3]);
            fa[4] = fmaf(w, t1.x, fa[4]);
            fa[5] = fmaf(w, t1.y, fa[5]);
            fa[6] = fmaf(w, t1.z, fa[6]);
            fa[7] = fmaf(w, t1.w, fa[7]);
        }

        float av = aff[n];
        #pragma unroll
        for (int j = 0; j < 4; ++j) {
            float o0 = fa[2 * j]     + av * Wa[fb + 2 * j]     + ba[fb + 2 * j];
            float o1 = fa[2 * j + 1] + av * Wa[fb + 2 * j + 1] + ba[fb + 2 * j + 1];
            pk[j] = (uint32_t)f2bf(o0) | ((uint32_t)f2bf(o1) << 16);
        }
    }
    *(uint4*)(comb + (size_t)n * 128 + fb) = make_uint4(pk[0], pk[1], pk[2], pk[3]);
}

// ---------------- tiny precompute GEMMs (weight folding) ---------------------
__global__ void small_mm(const float* __restrict__ A, const float* __restrict__ B,
                         float* __restrict__ C, int Mo, int No, int Ko)
{
    int gid = blockIdx.x * 256 + threadIdx.x;
    if (gid >= Mo * No) return;
    int j = gid / No, k = gid % No;
    float s = 0.f;
    for (int i = 0; i < Ko; ++i) s = fmaf(A[j * Ko + i], B[i * No + k], s);
    C[gid] = s;
}

__global__ void small_mv(const float* __restrict__ A, const float* __restrict__ v,
                         const float* __restrict__ b0, float* __restrict__ out,
                         int Mo, int Ko)
{
    int j = blockIdx.x * 256 + threadIdx.x;
    if (j >= Mo) return;
    float s = b0[j];
    for (int i = 0; i < Ko; ++i) s = fmaf(A[j * Ko + i], v[i], s);
    out[j] = s;
}

__global__ void f32_to_bf16_kernel(const float* __restrict__ in,
                                   ushort* __restrict__ out, int n)
{
    int i = blockIdx.x * 256 + threadIdx.x;
    if (i < n) out[i] = f2bf(in[i]);
}

// ---------------- fused MLP ---------------------------------------------------
// Per 128-row block: comb tile (LDS) -> h1 (LDS) -> h2 (LDS) -> out (global).
// A-operand in LDS uses the 16B-slot XOR swizzle: slot' = slot ^ (row & 7)
// (same involution on write and read). B-fragments are read straight from
// global (weights are L2-resident; every block reuses them).
// 512 threads = 8 waves in a 2(m) x 4(n) grid; wave tile 64x64 per stage.

template<int K>
__device__ __forceinline__ void mfma_stage(
    const ushort* As,                       // LDS [128][K] bf16, swizzled
    const ushort* __restrict__ W,           // global [>=wn*64+64][K] bf16
    int wm, int wn, int l15, int lhi, f32x4 (&acc)[4][4])
{
    #pragma unroll
    for (int kstep = 0; kstep < K / 32; ++kstep) {
        bf16x8 a[4], b[4];
        const int ks = kstep * 4 + lhi;     // 16B-slot index within row
        #pragma unroll
        for (int f = 0; f < 4; ++f) {
            const int ra = wm * 64 + f * 16 + l15;
            a[f] = *(const bf16x8*)&As[ra * K + ((ks ^ (ra & 7)) << 3)];
            const int rb = wn * 64 + f * 16 + l15;
            b[f] = *(const bf16x8*)&W[(size_t)rb * K + kstep * 32 + lhi * 8];
        }
        #pragma unroll
        for (int i = 0; i < 4; ++i)
            #pragma unroll
            for (int j = 0; j < 4; ++j)
                acc[i][j] = __builtin_amdgcn_mfma_f32_16x16x32_bf16(
                    a[i], b[j], acc[i][j], 0, 0, 0);
    }
}

// relu(acc + bias) -> bf16 into LDS [128][256] in the swizzled A layout
__device__ __forceinline__ void store_h_lds(
    ushort* H, const f32x4 (&acc)[4][4], const float* __restrict__ bias,
    int wm, int wn, int l15, int lhi)
{
    float bb[4];
    #pragma unroll
    for (int j = 0; j < 4; ++j) bb[j] = bias[wn * 64 + j * 16 + l15];
    #pragma unroll
    for (int i = 0; i < 4; ++i)
        #pragma unroll
        for (int r = 0; r < 4; ++r) {
            const int m = wm * 64 + i * 16 + lhi * 4 + r;
            #pragma unroll
            for (int j = 0; j < 4; ++j) {
                const int n = wn * 64 + j * 16 + l15;
                const int slot = n >> 3;
                H[m * 256 + (((slot ^ (m & 7)) << 3) | (n & 7))] =
                    f2bf(fmaxf(acc[i][j][r] + bb[j], 0.f));
            }
        }
}

__global__ __launch_bounds__(512, 2) void fused_mlp(
    const ushort* __restrict__ comb,    // [mpad,128] bf16
    const ushort* __restrict__ W1,      // [256,128] bf16 (folded W1·Wo·Wv)
    const float*  __restrict__ b1,      // [256] f32 (folded)
    const ushort* __restrict__ W2,      // [256,256] bf16
    const float*  __restrict__ b2,
    const ushort* __restrict__ W3,      // [1024,256] bf16
    const float*  __restrict__ b3,
    float* __restrict__ out, int npts)
{
    __shared__ ushort hA[128 * 256];    // 64 KB
    __shared__ ushort hB[128 * 256];    // 64 KB

    const int tid  = threadIdx.x;
    const int bm   = blockIdx.x;
    const int lane = tid & 63;
    const int wave = tid >> 6;
    const int wm   = wave >> 2, wn = wave & 3;     // 2x4 wave grid
    const int l15  = lane & 15, lhi = lane >> 4;

    // ---- stage comb tile [128][128] bf16 -> hB[0:32KB] ----
    // linear LDS dest + inverse-swizzled global source (rule #21)
    #pragma unroll
    for (int i = 0; i < 4; ++i) {
        const int c = tid + i * 512;               // 16B slot id, 0..2047
        const int r = c >> 4, s = c & 15;
        const ushort* g = comb + (size_t)(bm * 128 + r) * 128 + ((s ^ (r & 7)) * 8);
        __builtin_amdgcn_global_load_lds(
            (const __attribute__((address_space(1))) uint32_t*)g,
            (__attribute__((address_space(3))) uint32_t*)&hB[c * 8], 16, 0, 0);
    }
    __syncthreads();    // drains vmcnt(0)

    {   // stage 1: hA = relu(comb @ W1^T + b1)   [128x256], K=128
        f32x4 acc[4][4] = {};
        mfma_stage<128>(hB, W1, wm, wn, l15, lhi, acc);
        store_h_lds(hA, acc, b1, wm, wn, l15, lhi);
    }
    __syncthreads();

    {   // stage 2: hB = relu(hA @ W2^T + b2)     [128x256], K=256
        f32x4 acc[4][4] = {};
        mfma_stage<256>(hA, W2, wm, wn, l15, lhi, acc);
        store_h_lds(hB, acc, b2, wm, wn, l15, lhi);
    }
    __syncthreads();

    // stage 3: out = hB @ W3^T + b3, 4 chunks of 256 cols, split store.
    // C/D layout: col = lane&15 (n), row = (lane>>4)*4 + reg (m).
    #pragma unroll 1
    for (int ch = 0; ch < 4; ++ch) {
        f32x4 acc[4][4] = {};
        mfma_stage<256>(hB, W3 + (size_t)ch * 256 * 256, wm, wn, l15, lhi, acc);

        float bb[4];
        #pragma unroll
        for (int j = 0; j < 4; ++j) bb[j] = b3[ch * 256 + wn * 64 + j * 16 + l15];

        const int colg = ch * 256 + wn * 64 + l15;           // 0..1023
        float* plane   = out + ((ch >= 2) ? (size_t)npts * 512 : 0);
        const int ncol = colg - ((ch >= 2) ? 512 : 0);
        #pragma unroll
        for (int i = 0; i < 4; ++i)
            #pragma unroll
            for (int r = 0; r < 4; ++r) {
                const int m = bm * 128 + wm * 64 + i * 16 + lhi * 4 + r;
                if (m < npts) {
                    float* dst = plane + (size_t)m * 512 + ncol;
                    #pragma unroll
                    for (int j = 0; j < 4; ++j)
                        dst[j * 16] = acc[i][j][r] + bb[j];
                }
            }
    }
}

// ---------------- launch ------------------------------------------------------
extern "C" void kernel_launch(void* const* d_in, const int* in_sizes, int n_in,
                              void* d_out, int out_size, void* d_ws, size_t ws_size,
                              hipStream_t stream)
{
    const float* x     = (const float*)d_in[0];
    const float* aff   = (const float*)d_in[1];
    const float* table = (const float*)d_in[2];
    const float* Wa    = (const float*)d_in[3];
    const float* ba    = (const float*)d_in[4];
    // d_in[5..8] = Wq,bq,Wk,bk — unused (softmax over a single key == 1)
    const float* Wv    = (const float*)d_in[9];
    const float* bv    = (const float*)d_in[10];
    const float* Wo    = (const float*)d_in[11];
    const float* bo    = (const float*)d_in[12];
    const float* W1    = (const float*)d_in[13];
    const float* b1    = (const float*)d_in[14];
    const float* W2    = (const float*)d_in[15];
    const float* b2    = (const float*)d_in[16];
    const float* W3    = (const float*)d_in[17];
    const float* b3    = (const float*)d_in[18];
    const int npts = in_sizes[0] / 3;
    const int mb = (npts + 127) / 128;
    const int npts_pad = mb * 128;

    float* ws = (float*)d_ws;
    float*  Wvo  = ws;                          // 16384 f32
    float*  bvo  = ws + 16384;                  // 128
    float*  W1c  = ws + 16512;                  // 256*128 f32
    float*  b1c  = ws + 49280;                  // 256
    ushort* W1cb = (ushort*)(ws + 49536);       // 32768 bf16
    ushort* W2b  = (ushort*)(ws + 65920);       // 65536 bf16
    ushort* W3b  = (ushort*)(ws + 98688);       // 262144 bf16
    ushort* comb = (ushort*)(ws + 229760);      // [npts_pad,128] bf16

    // fold v/attn chain into W1: h1 = relu(comb @ (W1·Wo·Wv)^T + (W1·(Wo·bv+bo)+b1))
    small_mm<<<64, 256, 0, stream>>>(Wo, Wv, Wvo, 128, 128, 128);
    small_mv<<<1, 256, 0, stream>>>(Wo, bv, bo, bvo, 128, 128);
    small_mm<<<128, 256, 0, stream>>>(W1, Wvo, W1c, 256, 128, 128);
    small_mv<<<1, 256, 0, stream>>>(W1, bvo, b1, b1c, 256, 128);

    // bf16 weight planes
    f32_to_bf16_kernel<<<128, 256, 0, stream>>>(W1c, W1cb, 32768);
    f32_to_bf16_kernel<<<256, 256, 0, stream>>>(W2, W2b, 65536);
    f32_to_bf16_kernel<<<1024, 256, 0, stream>>>(W3, W3b, 262144);

    grid_encode_kernel<<<(npts_pad * 16) / 256, 256, 0, stream>>>(
        x, aff, table, Wa, ba, comb, npts, npts_pad);

    // one kernel for the whole MLP: h1/h2 never touch HBM
    fused_mlp<<<mb, 512, 0, stream>>>(comb, W1cb, b1c, W2b, b2, W3b, b3,
                                      (float*)d_out, npts);
}